// Round 5
// baseline (1684.371 us; speedup 1.0000x reference)
//
#include <hip/hip_runtime.h>
#include <hip/hip_bf16.h>
#include <math.h>

// NTM forward, fully fused: one block per batch element, T=64 steps in-kernel.
// Rev 6: identical structure to Rev 5 (1024 threads, ONE memory row per
// thread), plus an LDS pad that pushes LDS usage past 80 KB.
// Why: the AMDGPU register allocator sets its VGPR budget from the occupancy
// achievable under LDS constraints. At LDS=34KB / NT=1024, TWO 16-wave blocks
// fit per CU -> it targets 8 waves/SIMD -> budget 64 VGPRs -> M[64] spills to
// scratch (observed: VGPR_Count=64, WRITE_SIZE 13MB of spill writeback, and
// __launch_bounds__ / amdgpu_waves_per_eu failed to override across 3 rounds).
// Grid is 64 blocks on 256 CUs, so 2-blocks/CU co-residency NEVER happens --
// the allocator is optimizing for a ghost. Pushing LDS > 80KB makes 1 block/CU
// the computed ceiling -> target 4 waves/SIMD -> budget 128 VGPRs -> the
// ~100-register true demand (M[64] + butterfly cur[16] + temps) fits, no spill.

constexpr int kB  = 64;
constexpr int kT  = 64;
constexpr int kIN = 64;
constexpr int kC  = 256;
constexpr int kN  = 1024;
constexpr int kMV = 64;
constexpr int kOUT = 64;
constexpr int kHW = 198;   // write head raw dim: MV+6+2*MV
constexpr int kHR = 70;    // read head raw dim: MV+6
constexpr int NT  = 1024;  // threads per block (16 waves)
constexpr int NW  = NT / 64;
constexpr float kEPS = 1e-8f;

// packed (transposed) weight layout, offsets in elements
constexpr int kPWc = 0;                          // WcT [256][128]
constexpr int kPWw = kPWc + kC * 128;            // WwT [198][256] @ 32768
constexpr int kPWr = kPWw + kHW * kC;            // WrT [70][256]  @ 83456
constexpr int kPWf = kPWr + kHR * kC;            // WfT [64][320]  @ 101376
constexpr int kPTotal = kPWf + kOUT * (kC + kMV);  // 121856 elements
constexpr size_t kWsNeeded = 256 + (size_t)kPTotal * 4;  // fp32 worst case

__device__ __forceinline__ float ldf(const float* p, int i) { return p[i]; }
__device__ __forceinline__ float ldf(const __hip_bfloat16* p, int i) { return __bfloat162float(p[i]); }
__device__ __forceinline__ void stf(float* p, int i, float v) { p[i] = v; }
__device__ __forceinline__ void stf(__hip_bfloat16* p, int i, float v) { p[i] = __float2bfloat16(v); }

// 8 contiguous elements -> float[8]; 16B-aligned by construction.
__device__ __forceinline__ void ld8(const __hip_bfloat16* p, float* f) {
  uint4 u = *reinterpret_cast<const uint4*>(p);
  f[0] = __uint_as_float(u.x << 16); f[1] = __uint_as_float(u.x & 0xffff0000u);
  f[2] = __uint_as_float(u.y << 16); f[3] = __uint_as_float(u.y & 0xffff0000u);
  f[4] = __uint_as_float(u.z << 16); f[5] = __uint_as_float(u.z & 0xffff0000u);
  f[6] = __uint_as_float(u.w << 16); f[7] = __uint_as_float(u.w & 0xffff0000u);
}
__device__ __forceinline__ void ld8(const float* p, float* f) {
  float4 a = reinterpret_cast<const float4*>(p)[0];
  float4 b = reinterpret_cast<const float4*>(p)[1];
  f[0] = a.x; f[1] = a.y; f[2] = a.z; f[3] = a.w;
  f[4] = b.x; f[5] = b.y; f[6] = b.z; f[7] = b.w;
}

__device__ __forceinline__ float fexp(float v) { return __expf(v); }
__device__ __forceinline__ float sigmoidf_(float v) {
  return __fdividef(1.f, 1.f + __expf(-v));
}
__device__ __forceinline__ float softplusf_(float v) {
  return v > 20.f ? v : __logf(1.f + __expf(v));
}
__device__ __forceinline__ float ftanh(float v) {
  float a = fminf(fabsf(v), 15.f);          // tanh(15) == 1 in fp32
  float e = __expf(2.f * a);
  float t = 1.f - __fdividef(2.f, e + 1.f);
  return v < 0.f ? -t : t;
}

__device__ __forceinline__ float wsum(float v) {
  v += __shfl_xor(v, 32); v += __shfl_xor(v, 16); v += __shfl_xor(v, 8);
  v += __shfl_xor(v, 4);  v += __shfl_xor(v, 2);  v += __shfl_xor(v, 1);
  return v;
}
__device__ __forceinline__ float wmax(float v) {
  v = fmaxf(v, __shfl_xor(v, 32)); v = fmaxf(v, __shfl_xor(v, 16));
  v = fmaxf(v, __shfl_xor(v, 8));  v = fmaxf(v, __shfl_xor(v, 4));
  v = fmaxf(v, __shfl_xor(v, 2));  v = fmaxf(v, __shfl_xor(v, 1));
  return v;
}

struct alignas(16) Smem {
  float xS[kT * kIN];       // whole input sequence for this batch element (16KB)
  float c[kC];              // controller activations
  float k[kMV], kr[kMV], e[kMV], a[kMV], r[kMV];
  float partA[1088];        // flat partials arena (controller/heads/rv/output)
  float E[kN];              // unnormalized content softmax numerators
  float WP[kN];             // previous weights (for shift conv)
  float bcS[kC], bwS[kHW], brS[kHR], bfS[kOUT];   // biases (staged once)
  float red[3][NW];         // cross-wave reduction slots
  float scal[16];           // 0..6 write head: beta,g,gamma,s0,s1,s2,|k| ; 8..14 read head
  // Occupancy governor: pushes LDS past 80KB so only ONE 1024-thread block
  // fits per CU -> register allocator budgets 128 VGPRs instead of 64.
  // Never meaningfully written (guarded by a condition the compiler can't fold).
  float pad[16384];         // 64KB
};
static_assert(sizeof(Smem) > 80 * 1024, "pad must force 1 block/CU");
static_assert(sizeof(Smem) <= 160 * 1024, "LDS budget");

// One row per thread; 3 barriers. E/WP written before the gsum barrier; wg
// for shifted neighbors recomputed from E/WP with the identical fmaf
// expression -> bit-identical to materializing wg.
__device__ __forceinline__ float address1(Smem& sm, int tid, int lane, int wid,
                                          float sim, float g, float s0, float s1,
                                          float s2, float gamma, float wp) {
  float m = wmax(sim);
  if (lane == 0) sm.red[0][wid] = m;
  __syncthreads();                                   // A
  float gmax = sm.red[0][0];
  #pragma unroll
  for (int i = 1; i < NW; ++i) gmax = fmaxf(gmax, sm.red[0][i]);
  float e = fexp(sim - gmax);
  sm.E[tid] = e; sm.WP[tid] = wp;
  float sv = wsum(e);
  if (lane == 0) sm.red[1][wid] = sv;
  __syncthreads();                                   // B (covers gsum AND E/WP)
  float gsum = 0.f;
  #pragma unroll
  for (int i = 0; i < NW; ++i) gsum += sm.red[1][i];
  float inv = __fdividef(1.f, gsum);
  float wg = fmaf(g, fmaf(e, inv, -wp), wp);
  // circular conv: s0*w[n+1] + s1*w[n] + s2*w[n-1]  (SHIFTS = -1,0,+1)
  int np = (tid + 1) & (kN - 1), nm = (tid + kN - 1) & (kN - 1);
  float wgp = fmaf(g, fmaf(sm.E[np], inv, -sm.WP[np]), sm.WP[np]);
  float wgm = fmaf(g, fmaf(sm.E[nm], inv, -sm.WP[nm]), sm.WP[nm]);
  float ws = s0 * wgp + s1 * wg + s2 * wgm;
  float pw = fexp(gamma * __logf(ws + kEPS));
  float pv = wsum(pw);
  if (lane == 0) sm.red[2][wid] = pv;
  __syncthreads();                                   // C
  float psum = 0.f;
  #pragma unroll
  for (int i = 0; i < NW; ++i) psum += sm.red[2][i];
  return pw * __fdividef(1.f, psum);
}

// flag: 1 if buffers are bf16, 0 if fp32.  w_bias is a softmax -> sums to 1.
__global__ void detect_dtype(const void* wb, int* flag) {
  const unsigned short* u = (const unsigned short*)wb;
  int lane = threadIdx.x;
  float s = 0.f;
  for (int i = lane; i < kN; i += 64)
    s += __uint_as_float(((unsigned int)u[i]) << 16);
  s = wsum(s);
  if (lane == 0 && blockIdx.x == 0)
    *flag = (s > 0.75f && s < 1.25f) ? 1 : 0;
}

// Transpose-repack the four weight matrices into workspace (coalesced writes).
template <typename TD, int WANT>
__global__ void repack_w(const TD* __restrict__ Wc, const TD* __restrict__ Ww,
                         const TD* __restrict__ Wr, const TD* __restrict__ Wf,
                         TD* __restrict__ pk, const int* __restrict__ flag) {
  if (*flag != WANT) return;
  for (int idx = blockIdx.x * blockDim.x + threadIdx.x; idx < kPTotal;
       idx += gridDim.x * blockDim.x) {
    TD v;
    if (idx < kPWw) {                       // WcT[j][i] = Wc[i][j], [128][256] src
      int r = idx, j = r >> 7, i = r & 127;
      v = Wc[i * kC + j];
    } else if (idx < kPWr) {                // WwT[j][i] = Ww[i][j], [256][198] src
      int r = idx - kPWw, j = r >> 8, i = r & 255;
      v = Ww[i * kHW + j];
    } else if (idx < kPWf) {                // WrT[j][i] = Wr[i][j], [256][70] src
      int r = idx - kPWr, j = r >> 8, i = r & 255;
      v = Wr[i * kHR + j];
    } else {                                // WfT[j][i] = Wf[i][j], [320][64] src
      int r = idx - kPWf, j = r / 320, i = r % 320;
      v = Wf[i * kOUT + j];
    }
    pk[idx] = v;
  }
}

template <typename TD, int WANT, int PACKED>
__global__
__attribute__((amdgpu_flat_work_group_size(NT, NT), amdgpu_waves_per_eu(1, 4)))
void ntm_fused(
    const TD* __restrict__ x,
    const TD* __restrict__ Wc, const TD* __restrict__ bc,
    const TD* __restrict__ Wr, const TD* __restrict__ br,
    const TD* __restrict__ Ww, const TD* __restrict__ bw,
    const TD* __restrict__ Wf, const TD* __restrict__ bf,
    const TD* __restrict__ r_bias, const TD* __restrict__ w_bias,
    const TD* __restrict__ M_bias,
    const TD* __restrict__ pk,
    TD* __restrict__ out, const int* __restrict__ flag) {
  if (*flag != WANT) return;
  __shared__ Smem sm;
  const int tid  = threadIdx.x;
  const int b    = blockIdx.x;
  const int lane = tid & 63;
  const int wid  = tid >> 6;

  // keep the pad alive: flag is only ever 0 or 1, but the compiler can't prove it
  if (*flag == 2) { sm.pad[tid] = 0.f; __syncthreads(); out[tid] = (TD)sm.pad[NT - 1 - tid]; }

  const TD* pWcT = pk + kPWc;
  const TD* pWwT = pk + kPWw;
  const TD* pWrT = pk + kPWr;
  const TD* pWfT = pk + kPWf;

  // ---- one-time staging: whole x sequence (vectorized), biases, r_bias
  if (tid < 512) {
    float f[8]; ld8(x + (size_t)b * kT * kIN + tid * 8, f);
    #pragma unroll
    for (int u = 0; u < 8; ++u) sm.xS[tid * 8 + u] = f[u];
  }
  if (tid < kC)  sm.bcS[tid] = ldf(bc, tid);
  if (tid < kHW) sm.bwS[tid] = ldf(bw, tid);
  if (tid < kHR) sm.brS[tid] = ldf(br, tid);
  if (tid < kOUT) sm.bfS[tid] = ldf(bf, tid);
  if (tid < kMV) sm.r[tid] = ldf(r_bias, tid);

  // ---- init state: one M row (registers), row norm, prev weight
  float M[kMV];
  float n2 = 0.f;
  #pragma unroll
  for (int jb = 0; jb < kMV; jb += 8) {
    float f[8];
    ld8(M_bias + (size_t)tid * kMV + jb, f);
    #pragma unroll
    for (int u = 0; u < 8; ++u) {
      M[jb + u] = f[u];
      n2 = fmaf(f[u], f[u], n2);
    }
  }
  float wp = ldf(w_bias, tid);
  __syncthreads();

  #pragma unroll 1
  for (int t = 0; t < kT; ++t) {
    // ---- controller: c = tanh([x_t, r] @ Wc + bc); 256 outs x 4 partials of 32
    {
      const int j = tid & 255, p = tid >> 8;        // p wave-uniform
      const float* inp = (p < 2) ? &sm.xS[t * kIN + p * 32] : &sm.r[(p - 2) * 32];
      float s = 0.f;
      if constexpr (PACKED) {
        const TD* row = pWcT + j * 128 + p * 32;    // contiguous 32 elems
        #pragma unroll
        for (int q = 0; q < 4; ++q) {
          float f[8]; ld8(row + 8 * q, f);
          float4 xa = *(const float4*)&inp[8 * q];
          float4 xb = *(const float4*)&inp[8 * q + 4];
          s = fmaf(xa.x, f[0], s); s = fmaf(xa.y, f[1], s);
          s = fmaf(xa.z, f[2], s); s = fmaf(xa.w, f[3], s);
          s = fmaf(xb.x, f[4], s); s = fmaf(xb.y, f[5], s);
          s = fmaf(xb.z, f[6], s); s = fmaf(xb.w, f[7], s);
        }
      } else {
        #pragma unroll 8
        for (int i = 0; i < 32; ++i)
          s = fmaf(inp[i], ldf(Wc, (p * 32 + i) * kC + j), s);
      }
      sm.partA[p * 256 + j] = s;
    }
    __syncthreads();                                               // 1
    if (tid < kC)
      sm.c[tid] = ftanh(sm.partA[tid] + sm.partA[256 + tid] +
                        sm.partA[512 + tid] + sm.partA[768 + tid] + sm.bcS[tid]);
    __syncthreads();                                               // 2

    // ---- merged head GEMVs: 268 outs (Ww 0..197 | Wr 198..267), 2 partials of 128
    {
      const int o = tid & 511, p = tid >> 9;
      if (o < kHW + kHR) {
        const TD* row = (o < kHW) ? (pWwT + o * kC + p * 128)
                                  : (pWrT + (o - kHW) * kC + p * 128);
        float s = 0.f;
        if constexpr (PACKED) {
          #pragma unroll
          for (int q = 0; q < 16; ++q) {
            float f[8]; ld8(row + 8 * q, f);
            float4 ca = *(const float4*)&sm.c[p * 128 + 8 * q];
            float4 cb = *(const float4*)&sm.c[p * 128 + 8 * q + 4];
            s = fmaf(ca.x, f[0], s); s = fmaf(ca.y, f[1], s);
            s = fmaf(ca.z, f[2], s); s = fmaf(ca.w, f[3], s);
            s = fmaf(cb.x, f[4], s); s = fmaf(cb.y, f[5], s);
            s = fmaf(cb.z, f[6], s); s = fmaf(cb.w, f[7], s);
          }
        } else {
          #pragma unroll 8
          for (int i = 0; i < 128; ++i) {
            float wv = (o < kHW) ? ldf(Ww, (p * 128 + i) * kHW + o)
                                 : ldf(Wr, (p * 128 + i) * kHR + (o - kHW));
            s = fmaf(sm.c[p * 128 + i], wv, s);
          }
        }
        sm.partA[p * 272 + o] = s;
      }
    }
    __syncthreads();                                               // 3

    // ---- head params, fused with partial-sum + bias
    if (wid == 0) {                       // write key + |k|
      float kv = ftanh(sm.partA[lane] + sm.partA[272 + lane] + sm.bwS[lane]);
      sm.k[lane] = kv;
      float s = wsum(kv * kv);
      if (lane == 0) sm.scal[6] = sqrtf(s);
    } else if (wid == 1) {                // erase
      int o = 70 + lane;
      sm.e[lane] = sigmoidf_(sm.partA[o] + sm.partA[272 + o] + sm.bwS[o]);
    } else if (wid == 2) {                // add
      int o = 134 + lane;
      sm.a[lane] = ftanh(sm.partA[o] + sm.partA[272 + o] + sm.bwS[o]);
    } else if (wid == 3) {                // read key + |k|
      int o = kHW + lane;
      float kv = ftanh(sm.partA[o] + sm.partA[272 + o] + sm.brS[lane]);
      sm.kr[lane] = kv;
      float s = wsum(kv * kv);
      if (lane == 0) sm.scal[14] = sqrtf(s);
    } else if (tid == 256) {              // write head scalars (o = 64..69)
      float h64 = sm.partA[64] + sm.partA[272 + 64] + sm.bwS[64];
      float h65 = sm.partA[65] + sm.partA[272 + 65] + sm.bwS[65];
      float a0  = sm.partA[66] + sm.partA[272 + 66] + sm.bwS[66];
      float a1  = sm.partA[67] + sm.partA[272 + 67] + sm.bwS[67];
      float a2  = sm.partA[68] + sm.partA[272 + 68] + sm.bwS[68];
      float h69 = sm.partA[69] + sm.partA[272 + 69] + sm.bwS[69];
      sm.scal[0] = softplusf_(h64);
      sm.scal[1] = sigmoidf_(h65);
      sm.scal[2] = 1.f + softplusf_(h69);
      float mx = fmaxf(a0, fmaxf(a1, a2));
      float e0 = fexp(a0 - mx), e1 = fexp(a1 - mx), e2 = fexp(a2 - mx);
      float d = __fdividef(1.f, e0 + e1 + e2);
      sm.scal[3] = e0 * d; sm.scal[4] = e1 * d; sm.scal[5] = e2 * d;
    } else if (tid == 320) {              // read head scalars (o = 262..267)
      float h64 = sm.partA[kHW + 64] + sm.partA[272 + kHW + 64] + sm.brS[64];
      float h65 = sm.partA[kHW + 65] + sm.partA[272 + kHW + 65] + sm.brS[65];
      float a0  = sm.partA[kHW + 66] + sm.partA[272 + kHW + 66] + sm.brS[66];
      float a1  = sm.partA[kHW + 67] + sm.partA[272 + kHW + 67] + sm.brS[67];
      float a2  = sm.partA[kHW + 68] + sm.partA[272 + kHW + 68] + sm.brS[68];
      float h69 = sm.partA[kHW + 69] + sm.partA[272 + kHW + 69] + sm.brS[69];
      sm.scal[8]  = softplusf_(h64);
      sm.scal[9]  = sigmoidf_(h65);
      sm.scal[10] = 1.f + softplusf_(h69);
      float mx = fmaxf(a0, fmaxf(a1, a2));
      float e0 = fexp(a0 - mx), e1 = fexp(a1 - mx), e2 = fexp(a2 - mx);
      float d = __fdividef(1.f, e0 + e1 + e2);
      sm.scal[11] = e0 * d; sm.scal[12] = e1 * d; sm.scal[13] = e2 * d;
    }
    __syncthreads();                                               // 4

    // ---- write head addressing (one row per thread)
    float ww;
    {
      float beta = sm.scal[0], g = sm.scal[1], gamma = sm.scal[2];
      float s0 = sm.scal[3], s1 = sm.scal[4], s2 = sm.scal[5], kn = sm.scal[6];
      float d0 = 0.f;
      #pragma unroll
      for (int jb = 0; jb < kMV; jb += 4) {
        float4 kv = *(const float4*)&sm.k[jb];
        d0 = fmaf(M[jb], kv.x, d0);     d0 = fmaf(M[jb + 1], kv.y, d0);
        d0 = fmaf(M[jb + 2], kv.z, d0); d0 = fmaf(M[jb + 3], kv.w, d0);
      }
      float sim = beta * d0 / (sqrtf(n2) * kn + kEPS);
      ww = address1(sm, tid, lane, wid, sim, g, s0, s1, s2, gamma, wp);  // 5,6,7
    }

    // ---- memory update, fused with read-head dot + new row norm
    float dr = 0.f, nn = 0.f;
    #pragma unroll
    for (int jb = 0; jb < kMV; jb += 4) {
      float4 ev = *(const float4*)&sm.e[jb];
      float4 av = *(const float4*)&sm.a[jb];
      float4 kv = *(const float4*)&sm.kr[jb];
      {
        float m = fmaf(ww, fmaf(-ev.x, M[jb], av.x), M[jb]);
        M[jb] = m; dr = fmaf(m, kv.x, dr); nn = fmaf(m, m, nn);
      }
      {
        float m = fmaf(ww, fmaf(-ev.y, M[jb + 1], av.y), M[jb + 1]);
        M[jb + 1] = m; dr = fmaf(m, kv.y, dr); nn = fmaf(m, m, nn);
      }
      {
        float m = fmaf(ww, fmaf(-ev.z, M[jb + 2], av.z), M[jb + 2]);
        M[jb + 2] = m; dr = fmaf(m, kv.z, dr); nn = fmaf(m, m, nn);
      }
      {
        float m = fmaf(ww, fmaf(-ev.w, M[jb + 3], av.w), M[jb + 3]);
        M[jb + 3] = m; dr = fmaf(m, kv.w, dr); nn = fmaf(m, m, nn);
      }
    }

    // ---- read head addressing (prev weights = write weights)
    float wr;
    {
      float beta = sm.scal[8], g = sm.scal[9], gamma = sm.scal[10];
      float s0 = sm.scal[11], s1 = sm.scal[12], s2 = sm.scal[13], kn = sm.scal[14];
      float sim = beta * dr / (sqrtf(nn) * kn + kEPS);
      wr = address1(sm, tid, lane, wid, sim, g, s0, s1, s2, gamma, ww);  // 8,9,10
    }
    wp = wr; n2 = nn;   // carry state

    // ---- read vector r[j] = sum_n w_r[n] M[n][j]
    // two 32-column butterfly passes; after 5 stages + cross-half add, lane l
    // (l<32) holds the wave's column sum. All indices compile-time (rule #20).
    {
      // pass A: columns 0..31 (from M[0..31])
      {
        float cur[16];
        const int b0 = lane & 1;
        #pragma unroll
        for (int q = 0; q < 16; ++q) {
          float v0 = wr * M[2 * q], v1 = wr * M[2 * q + 1];
          float keep = b0 ? v1 : v0, send = b0 ? v0 : v1;
          cur[q] = keep + __shfl_xor(send, 1);
        }
        #pragma unroll
        for (int st = 1; st < 5; ++st) {
          const int d = 1 << st;
          const int bb = (lane >> st) & 1;
          #pragma unroll
          for (int q = 0; q < (16 >> st); ++q) {
            float x0 = cur[2 * q], x1 = cur[2 * q + 1];
            float keep = bb ? x1 : x0, send = bb ? x0 : x1;
            cur[q] = keep + __shfl_xor(send, d);
          }
        }
        float tot = cur[0] + __shfl_xor(cur[0], 32);
        if (lane < 32) sm.partA[wid * 64 + lane] = tot;
      }
      // pass B: columns 32..63 (from M[32..63])
      {
        float cur[16];
        const int b0 = lane & 1;
        #pragma unroll
        for (int q = 0; q < 16; ++q) {
          float v0 = wr * M[32 + 2 * q], v1 = wr * M[32 + 2 * q + 1];
          float keep = b0 ? v1 : v0, send = b0 ? v0 : v1;
          cur[q] = keep + __shfl_xor(send, 1);
        }
        #pragma unroll
        for (int st = 1; st < 5; ++st) {
          const int d = 1 << st;
          const int bb = (lane >> st) & 1;
          #pragma unroll
          for (int q = 0; q < (16 >> st); ++q) {
            float x0 = cur[2 * q], x1 = cur[2 * q + 1];
            float keep = bb ? x1 : x0, send = bb ? x0 : x1;
            cur[q] = keep + __shfl_xor(send, d);
          }
        }
        float tot = cur[0] + __shfl_xor(cur[0], 32);
        if (lane < 32) sm.partA[wid * 64 + 32 + lane] = tot;
      }
    }
    __syncthreads();                                               // 11
    if (tid < kMV) {
      float s = sm.partA[tid];
      #pragma unroll
      for (int w = 1; w < NW; ++w) s += sm.partA[w * 64 + tid];
      sm.r[tid] = s;
    }
    __syncthreads();                                               // 12

    // ---- output: sigmoid([c, r] @ Wf + bf); 64 outs x 8 partials of 40
    if (tid < 512) {
      const int j = tid & 63, p = tid >> 6;
      float s = 0.f;
      if constexpr (PACKED) {
        const TD* row = pWfT + j * (kC + kMV) + p * 40;
        #pragma unroll
        for (int q = 0; q < 5; ++q) {
          int idx0 = p * 40 + 8 * q;   // multiple of 8; c/r boundary chunk-aligned
          const float* src = (idx0 < kC) ? &sm.c[idx0] : &sm.r[idx0 - kC];
          float f[8]; ld8(row + 8 * q, f);
          float4 va = *(const float4*)src;
          float4 vb = *(const float4*)(src + 4);
          s = fmaf(va.x, f[0], s); s = fmaf(va.y, f[1], s);
          s = fmaf(va.z, f[2], s); s = fmaf(va.w, f[3], s);
          s = fmaf(vb.x, f[4], s); s = fmaf(vb.y, f[5], s);
          s = fmaf(vb.z, f[6], s); s = fmaf(vb.w, f[7], s);
        }
      } else {
        #pragma unroll
        for (int i = 0; i < 40; ++i) {
          int idx = p * 40 + i;
          float v = (idx < kC) ? sm.c[idx] : sm.r[idx - kC];
          s = fmaf(v, ldf(Wf, idx * kOUT + j), s);
        }
      }
      sm.partA[p * 64 + j] = s;
    }
    __syncthreads();                                               // 13
    if (tid < kOUT) {
      float s = sm.bfS[tid];
      #pragma unroll
      for (int p = 0; p < 8; ++p) s += sm.partA[p * 64 + tid];
      stf(out, (b * kT + t) * kOUT + tid, sigmoidf_(s));
    }
    __syncthreads();                                               // 14
  }
}

template <typename TD, int WANT, int PACKED>
static void launch_variant(void* const* d_in, void* d_out, const int* flag,
                           const void* pk, hipStream_t stream) {
  ntm_fused<TD, WANT, PACKED><<<dim3(kB), dim3(NT), 0, stream>>>(
      (const TD*)d_in[0], (const TD*)d_in[1], (const TD*)d_in[2],
      (const TD*)d_in[3], (const TD*)d_in[4], (const TD*)d_in[5],
      (const TD*)d_in[6], (const TD*)d_in[7], (const TD*)d_in[8],
      (const TD*)d_in[9], (const TD*)d_in[10], (const TD*)d_in[11],
      (const TD*)pk, (TD*)d_out, flag);
}

extern "C" void kernel_launch(void* const* d_in, const int* in_sizes, int n_in,
                              void* d_out, int out_size, void* d_ws, size_t ws_size,
                              hipStream_t stream) {
  (void)in_sizes; (void)n_in; (void)out_size;
  int* flag = (int*)d_ws;
  detect_dtype<<<dim3(1), dim3(64), 0, stream>>>(d_in[10], flag);
  if (ws_size >= kWsNeeded) {
    void* pk = (void*)((char*)d_ws + 256);
    repack_w<__hip_bfloat16, 1><<<dim3(256), dim3(256), 0, stream>>>(
        (const __hip_bfloat16*)d_in[1], (const __hip_bfloat16*)d_in[5],
        (const __hip_bfloat16*)d_in[3], (const __hip_bfloat16*)d_in[7],
        (__hip_bfloat16*)pk, flag);
    repack_w<float, 0><<<dim3(256), dim3(256), 0, stream>>>(
        (const float*)d_in[1], (const float*)d_in[5],
        (const float*)d_in[3], (const float*)d_in[7],
        (float*)pk, flag);
    launch_variant<__hip_bfloat16, 1, 1>(d_in, d_out, flag, pk, stream);
    launch_variant<float, 0, 1>(d_in, d_out, flag, pk, stream);
  } else {
    launch_variant<__hip_bfloat16, 1, 0>(d_in, d_out, flag, nullptr, stream);
    launch_variant<float, 0, 0>(d_in, d_out, flag, nullptr, stream);
  }
}

// Round 6
// 1465.824 us; speedup vs baseline: 1.1491x; 1.1491x over previous
//
#include <hip/hip_runtime.h>
#include <hip/hip_bf16.h>
#include <math.h>

// NTM forward, fully fused: one block per batch element, T=64 steps in-kernel.
// Rev 7: stop fighting the register allocator -- fit inside what it grants.
// Evidence (5 rounds): backend pins VGPR budget at 128 for NT=512 and 64 for
// NT=1024, ignoring __launch_bounds__, amdgpu_waves_per_eu, and LDS occupancy
// (99KB pad round: budget unchanged). M never fit -> compiler-spilled to
// scratch with no ILP = the ~50k stall cycles/step.
// Design: NT=512, M split hierarchically:
//   - rows 0..511   : one row per thread in REGISTERS (64 VGPRs, fits in 128)
//   - rows 512..1023: one row per thread in LDS (512x64 fp32 = 128KB)
// LDS M layout is [col-block][row][float4]: lane r reads bytes b*8192+16r ->
// lane-contiguous ds_read_b128/ds_write_b128, conflict-free by construction
// (a [row][64] layout would be an 8-way bank conflict on every access).
// x staged from LDS dropped (x_t is 128B/step, read direct from global, L1-hot)
// to make LDS room. Phase structure = round-2's best (14 barriers/step).

constexpr int kB  = 64;
constexpr int kT  = 64;
constexpr int kIN = 64;
constexpr int kC  = 256;
constexpr int kN  = 1024;
constexpr int kMV = 64;
constexpr int kOUT = 64;
constexpr int kHW = 198;   // write head raw dim: MV+6+2*MV
constexpr int kHR = 70;    // read head raw dim: MV+6
constexpr int NT  = 512;   // threads per block (8 waves)
constexpr int NW  = NT / 64;
constexpr float kEPS = 1e-8f;

// packed (transposed) weight layout, offsets in elements
constexpr int kPWc = 0;                          // WcT [256][128]
constexpr int kPWw = kPWc + kC * 128;            // WwT [198][256] @ 32768
constexpr int kPWr = kPWw + kHW * kC;            // WrT [70][256]  @ 83456
constexpr int kPWf = kPWr + kHR * kC;            // WfT [64][320]  @ 101376
constexpr int kPTotal = kPWf + kOUT * (kC + kMV);  // 121856 elements
constexpr size_t kWsNeeded = 256 + (size_t)kPTotal * 4;  // fp32 worst case

__device__ __forceinline__ float ldf(const float* p, int i) { return p[i]; }
__device__ __forceinline__ float ldf(const __hip_bfloat16* p, int i) { return __bfloat162float(p[i]); }
__device__ __forceinline__ void stf(float* p, int i, float v) { p[i] = v; }
__device__ __forceinline__ void stf(__hip_bfloat16* p, int i, float v) { p[i] = __float2bfloat16(v); }

// 8 contiguous elements -> float[8]; 16B-aligned by construction.
__device__ __forceinline__ void ld8(const __hip_bfloat16* p, float* f) {
  uint4 u = *reinterpret_cast<const uint4*>(p);
  f[0] = __uint_as_float(u.x << 16); f[1] = __uint_as_float(u.x & 0xffff0000u);
  f[2] = __uint_as_float(u.y << 16); f[3] = __uint_as_float(u.y & 0xffff0000u);
  f[4] = __uint_as_float(u.z << 16); f[5] = __uint_as_float(u.z & 0xffff0000u);
  f[6] = __uint_as_float(u.w << 16); f[7] = __uint_as_float(u.w & 0xffff0000u);
}
__device__ __forceinline__ void ld8(const float* p, float* f) {
  float4 a = reinterpret_cast<const float4*>(p)[0];
  float4 b = reinterpret_cast<const float4*>(p)[1];
  f[0] = a.x; f[1] = a.y; f[2] = a.z; f[3] = a.w;
  f[4] = b.x; f[5] = b.y; f[6] = b.z; f[7] = b.w;
}

__device__ __forceinline__ float fexp(float v) { return __expf(v); }
__device__ __forceinline__ float sigmoidf_(float v) {
  return __fdividef(1.f, 1.f + __expf(-v));
}
__device__ __forceinline__ float softplusf_(float v) {
  return v > 20.f ? v : __logf(1.f + __expf(v));
}
__device__ __forceinline__ float ftanh(float v) {
  float a = fminf(fabsf(v), 15.f);          // tanh(15) == 1 in fp32
  float e = __expf(2.f * a);
  float t = 1.f - __fdividef(2.f, e + 1.f);
  return v < 0.f ? -t : t;
}

__device__ __forceinline__ float wsum(float v) {
  v += __shfl_xor(v, 32); v += __shfl_xor(v, 16); v += __shfl_xor(v, 8);
  v += __shfl_xor(v, 4);  v += __shfl_xor(v, 2);  v += __shfl_xor(v, 1);
  return v;
}
__device__ __forceinline__ float wmax(float v) {
  v = fmaxf(v, __shfl_xor(v, 32)); v = fmaxf(v, __shfl_xor(v, 16));
  v = fmaxf(v, __shfl_xor(v, 8));  v = fmaxf(v, __shfl_xor(v, 4));
  v = fmaxf(v, __shfl_xor(v, 2));  v = fmaxf(v, __shfl_xor(v, 1));
  return v;
}

struct alignas(16) Smem {
  // M rows 512..1023: [block b=col/4][row r][4 floats]; lane-contiguous b128.
  float M1s[16 * 512 * 4];   // 128 KB
  float c[kC];               // controller activations
  float k[kMV], kr[kMV], e[kMV], a[kMV], r[kMV];
  float part[8][kC];         // GEMM partials / read-vector wave partials
  float E[kN];               // unnormalized content softmax numerators
  float WP[kN];              // previous weights (for shift conv)
  float bcS[kC], bwS[kHW], brS[kHR], bfS[kOUT];   // biases (staged once)
  float red[3][NW];          // cross-wave reduction slots
  float scal[16];            // 0..6 write head; 8..14 read head
};
static_assert(sizeof(Smem) <= 160 * 1024, "LDS budget");

__device__ __forceinline__ int m1idx(int blk, int row) { return (blk * 512 + row) * 4; }

// Two rows per thread (reg row value sim0, LDS row value sim1); 3 barriers.
// E/WP written before the gsum barrier; wg for shifted neighbors recomputed
// from E/WP with the identical fmaf expression -> bit-identical.
__device__ __forceinline__ void address2(Smem& sm, int tid, int lane, int wid,
                                         float sim0, float sim1,
                                         float g, float s0, float s1, float s2, float gamma,
                                         float wp0, float wp1,
                                         float& w0, float& w1) {
  float m = wmax(fmaxf(sim0, sim1));
  if (lane == 0) sm.red[0][wid] = m;
  __syncthreads();                                   // A
  float gmax = sm.red[0][0];
  #pragma unroll
  for (int i = 1; i < NW; ++i) gmax = fmaxf(gmax, sm.red[0][i]);
  float e0 = fexp(sim0 - gmax), e1 = fexp(sim1 - gmax);
  sm.E[tid] = e0; sm.E[tid + NT] = e1;
  sm.WP[tid] = wp0; sm.WP[tid + NT] = wp1;
  float sv = wsum(e0 + e1);
  if (lane == 0) sm.red[1][wid] = sv;
  __syncthreads();                                   // B (covers gsum AND E/WP)
  float gsum = 0.f;
  #pragma unroll
  for (int i = 0; i < NW; ++i) gsum += sm.red[1][i];
  float inv = __fdividef(1.f, gsum);
  float wg0 = fmaf(g, fmaf(e0, inv, -wp0), wp0);
  float wg1 = fmaf(g, fmaf(e1, inv, -wp1), wp1);
  // circular conv: s0*w[n+1] + s1*w[n] + s2*w[n-1]  (SHIFTS = -1,0,+1)
  int np = (tid + 1) & (kN - 1), nm = (tid + kN - 1) & (kN - 1);
  float wgp = fmaf(g, fmaf(sm.E[np], inv, -sm.WP[np]), sm.WP[np]);
  float wgm = fmaf(g, fmaf(sm.E[nm], inv, -sm.WP[nm]), sm.WP[nm]);
  float ws0 = s0 * wgp + s1 * wg0 + s2 * wgm;
  int npb = (tid + NT + 1) & (kN - 1), nmb = (tid + NT - 1) & (kN - 1);
  float wgpb = fmaf(g, fmaf(sm.E[npb], inv, -sm.WP[npb]), sm.WP[npb]);
  float wgmb = fmaf(g, fmaf(sm.E[nmb], inv, -sm.WP[nmb]), sm.WP[nmb]);
  float ws1 = s0 * wgpb + s1 * wg1 + s2 * wgmb;
  float p0 = fexp(gamma * __logf(ws0 + kEPS));
  float p1 = fexp(gamma * __logf(ws1 + kEPS));
  float pv = wsum(p0 + p1);
  if (lane == 0) sm.red[2][wid] = pv;
  __syncthreads();                                   // C
  float psum = 0.f;
  #pragma unroll
  for (int i = 0; i < NW; ++i) psum += sm.red[2][i];
  float ipn = __fdividef(1.f, psum);
  w0 = p0 * ipn; w1 = p1 * ipn;
}

// flag: 1 if buffers are bf16, 0 if fp32.  w_bias is a softmax -> sums to 1.
__global__ void detect_dtype(const void* wb, int* flag) {
  const unsigned short* u = (const unsigned short*)wb;
  int lane = threadIdx.x;
  float s = 0.f;
  for (int i = lane; i < kN; i += 64)
    s += __uint_as_float(((unsigned int)u[i]) << 16);
  s = wsum(s);
  if (lane == 0 && blockIdx.x == 0)
    *flag = (s > 0.75f && s < 1.25f) ? 1 : 0;
}

// Transpose-repack the four weight matrices into workspace (coalesced writes).
template <typename TD, int WANT>
__global__ void repack_w(const TD* __restrict__ Wc, const TD* __restrict__ Ww,
                         const TD* __restrict__ Wr, const TD* __restrict__ Wf,
                         TD* __restrict__ pk, const int* __restrict__ flag) {
  if (*flag != WANT) return;
  for (int idx = blockIdx.x * blockDim.x + threadIdx.x; idx < kPTotal;
       idx += gridDim.x * blockDim.x) {
    TD v;
    if (idx < kPWw) {                       // WcT[j][i] = Wc[i][j], [128][256] src
      int r = idx, j = r >> 7, i = r & 127;
      v = Wc[i * kC + j];
    } else if (idx < kPWr) {                // WwT[j][i] = Ww[i][j], [256][198] src
      int r = idx - kPWw, j = r >> 8, i = r & 255;
      v = Ww[i * kHW + j];
    } else if (idx < kPWf) {                // WrT[j][i] = Wr[i][j], [256][70] src
      int r = idx - kPWr, j = r >> 8, i = r & 255;
      v = Wr[i * kHR + j];
    } else {                                // WfT[j][i] = Wf[i][j], [320][64] src
      int r = idx - kPWf, j = r / 320, i = r % 320;
      v = Wf[i * kOUT + j];
    }
    pk[idx] = v;
  }
}

template <typename TD, int WANT, int PACKED>
__global__ __launch_bounds__(NT, 1) void ntm_fused(
    const TD* __restrict__ x,
    const TD* __restrict__ Wc, const TD* __restrict__ bc,
    const TD* __restrict__ Wr, const TD* __restrict__ br,
    const TD* __restrict__ Ww, const TD* __restrict__ bw,
    const TD* __restrict__ Wf, const TD* __restrict__ bf,
    const TD* __restrict__ r_bias, const TD* __restrict__ w_bias,
    const TD* __restrict__ M_bias,
    const TD* __restrict__ pk,
    TD* __restrict__ out, const int* __restrict__ flag) {
  if (*flag != WANT) return;
  __shared__ Smem sm;
  const int tid  = threadIdx.x;
  const int b    = blockIdx.x;
  const int lane = tid & 63;
  const int wid  = tid >> 6;

  const TD* pWcT = pk + kPWc;
  const TD* pWwT = pk + kPWw;
  const TD* pWrT = pk + kPWr;
  const TD* pWfT = pk + kPWf;

  // ---- one-time staging: biases, r_bias
  if (tid < kC)  sm.bcS[tid] = ldf(bc, tid);
  if (tid < kHW) sm.bwS[tid] = ldf(bw, tid);
  if (tid < kHR) sm.brS[tid] = ldf(br, tid);
  if (tid < kOUT) sm.bfS[tid] = ldf(bf, tid);
  if (tid < kMV) sm.r[tid] = ldf(r_bias, tid);

  // ---- init state: reg row (tid) + LDS row (tid+512), norms, prev weights
  float M0[kMV];
  float n2_0 = 0.f, n2_1 = 0.f;
  #pragma unroll
  for (int jb = 0; jb < kMV; jb += 8) {
    float f0[8], f1[8];
    ld8(M_bias + (size_t)tid * kMV + jb, f0);
    ld8(M_bias + (size_t)(tid + NT) * kMV + jb, f1);
    #pragma unroll
    for (int u = 0; u < 8; ++u) {
      M0[jb + u] = f0[u];
      n2_0 = fmaf(f0[u], f0[u], n2_0);
      n2_1 = fmaf(f1[u], f1[u], n2_1);
    }
    float4 w0 = make_float4(f1[0], f1[1], f1[2], f1[3]);
    float4 w1 = make_float4(f1[4], f1[5], f1[6], f1[7]);
    *(float4*)&sm.M1s[m1idx(jb >> 2, tid)] = w0;
    *(float4*)&sm.M1s[m1idx((jb >> 2) + 1, tid)] = w1;
  }
  float wp0 = ldf(w_bias, tid);
  float wp1 = ldf(w_bias, tid + NT);
  __syncthreads();

  #pragma unroll 1
  for (int t = 0; t < kT; ++t) {
    // ---- controller: c = tanh([x_t, r] @ Wc + bc); 256 outs x 2 partials of 64
    {
      const int j = tid & 255, p = tid >> 8;       // p wave-uniform
      const TD* xrow = x + ((size_t)b * kT + t) * kIN;
      float s = 0.f;
      if constexpr (PACKED) {
        const TD* row = pWcT + j * 128 + p * 64;   // contiguous 64 elems
        #pragma unroll
        for (int q = 0; q < 8; ++q) {
          float f[8]; ld8(row + 8 * q, f);
          float xv[8];
          if (p == 0) {
            ld8(xrow + 8 * q, xv);                 // x_t direct from global (L1-hot)
          } else {
            float4 a4 = *(const float4*)&sm.r[8 * q];
            float4 b4 = *(const float4*)&sm.r[8 * q + 4];
            xv[0] = a4.x; xv[1] = a4.y; xv[2] = a4.z; xv[3] = a4.w;
            xv[4] = b4.x; xv[5] = b4.y; xv[6] = b4.z; xv[7] = b4.w;
          }
          #pragma unroll
          for (int u = 0; u < 8; ++u) s = fmaf(xv[u], f[u], s);
        }
      } else {
        #pragma unroll 8
        for (int i = 0; i < 64; ++i) {
          float xv = (p == 0) ? ldf(x, ((size_t)b * kT + t) * kIN + i) : sm.r[i];
          s = fmaf(xv, ldf(Wc, (p * 64 + i) * kC + j), s);
        }
      }
      sm.part[p][j] = s;
    }
    __syncthreads();                                               // 1
    if (tid < kC) sm.c[tid] = ftanh(sm.part[0][tid] + sm.part[1][tid] + sm.bcS[tid]);
    __syncthreads();                                               // 2

    // ---- head GEMVs: hw = c @ Ww + bw (198), hr = c @ Wr + br (70)
    {
      const int j = tid & 255, p = tid >> 8;
      if (j < kHW) {
        float s = 0.f;
        if constexpr (PACKED) {
          const TD* row = pWwT + j * kC + p * 128;
          #pragma unroll
          for (int q = 0; q < 16; ++q) {
            float f[8]; ld8(row + 8 * q, f);
            float4 ca = *(const float4*)&sm.c[p * 128 + 8 * q];
            float4 cb = *(const float4*)&sm.c[p * 128 + 8 * q + 4];
            s = fmaf(ca.x, f[0], s); s = fmaf(ca.y, f[1], s);
            s = fmaf(ca.z, f[2], s); s = fmaf(ca.w, f[3], s);
            s = fmaf(cb.x, f[4], s); s = fmaf(cb.y, f[5], s);
            s = fmaf(cb.z, f[6], s); s = fmaf(cb.w, f[7], s);
          }
        } else {
          #pragma unroll 8
          for (int i = 0; i < 128; ++i)
            s = fmaf(sm.c[p * 128 + i], ldf(Ww, (p * 128 + i) * kHW + j), s);
        }
        sm.part[p][j] = s;
      }
      if (j < kHR) {
        float s = 0.f;
        if constexpr (PACKED) {
          const TD* row = pWrT + j * kC + p * 128;
          #pragma unroll
          for (int q = 0; q < 16; ++q) {
            float f[8]; ld8(row + 8 * q, f);
            float4 ca = *(const float4*)&sm.c[p * 128 + 8 * q];
            float4 cb = *(const float4*)&sm.c[p * 128 + 8 * q + 4];
            s = fmaf(ca.x, f[0], s); s = fmaf(ca.y, f[1], s);
            s = fmaf(ca.z, f[2], s); s = fmaf(ca.w, f[3], s);
            s = fmaf(cb.x, f[4], s); s = fmaf(cb.y, f[5], s);
            s = fmaf(cb.z, f[6], s); s = fmaf(cb.w, f[7], s);
          }
        } else {
          #pragma unroll 8
          for (int i = 0; i < 128; ++i)
            s = fmaf(sm.c[p * 128 + i], ldf(Wr, (p * 128 + i) * kHR + j), s);
        }
        sm.part[2 + p][j] = s;
      }
    }
    __syncthreads();                                               // 3

    // ---- head params, fused with partial-sum + bias
    if (wid == 0) {                       // write key + |k|
      float kv = ftanh(sm.part[0][lane] + sm.part[1][lane] + sm.bwS[lane]);
      sm.k[lane] = kv;
      float s = wsum(kv * kv);
      if (lane == 0) sm.scal[6] = sqrtf(s);
    } else if (wid == 1) {                // erase
      int j = 70 + lane;
      sm.e[lane] = sigmoidf_(sm.part[0][j] + sm.part[1][j] + sm.bwS[j]);
    } else if (wid == 2) {                // add
      int j = 134 + lane;
      sm.a[lane] = ftanh(sm.part[0][j] + sm.part[1][j] + sm.bwS[j]);
    } else if (wid == 3) {                // read key + |k|
      float kv = ftanh(sm.part[2][lane] + sm.part[3][lane] + sm.brS[lane]);
      sm.kr[lane] = kv;
      float s = wsum(kv * kv);
      if (lane == 0) sm.scal[14] = sqrtf(s);
    } else if (tid == 256) {              // write head scalars
      float h64 = sm.part[0][64] + sm.part[1][64] + sm.bwS[64];
      float h65 = sm.part[0][65] + sm.part[1][65] + sm.bwS[65];
      float a0  = sm.part[0][66] + sm.part[1][66] + sm.bwS[66];
      float a1  = sm.part[0][67] + sm.part[1][67] + sm.bwS[67];
      float a2  = sm.part[0][68] + sm.part[1][68] + sm.bwS[68];
      float h69 = sm.part[0][69] + sm.part[1][69] + sm.bwS[69];
      sm.scal[0] = softplusf_(h64);
      sm.scal[1] = sigmoidf_(h65);
      sm.scal[2] = 1.f + softplusf_(h69);
      float mx = fmaxf(a0, fmaxf(a1, a2));
      float e0 = fexp(a0 - mx), e1 = fexp(a1 - mx), e2 = fexp(a2 - mx);
      float d = __fdividef(1.f, e0 + e1 + e2);
      sm.scal[3] = e0 * d; sm.scal[4] = e1 * d; sm.scal[5] = e2 * d;
    } else if (tid == 320) {              // read head scalars
      float h64 = sm.part[2][64] + sm.part[3][64] + sm.brS[64];
      float h65 = sm.part[2][65] + sm.part[3][65] + sm.brS[65];
      float a0  = sm.part[2][66] + sm.part[3][66] + sm.brS[66];
      float a1  = sm.part[2][67] + sm.part[3][67] + sm.brS[67];
      float a2  = sm.part[2][68] + sm.part[3][68] + sm.brS[68];
      float h69 = sm.part[2][69] + sm.part[3][69] + sm.brS[69];
      sm.scal[8]  = softplusf_(h64);
      sm.scal[9]  = sigmoidf_(h65);
      sm.scal[10] = 1.f + softplusf_(h69);
      float mx = fmaxf(a0, fmaxf(a1, a2));
      float e0 = fexp(a0 - mx), e1 = fexp(a1 - mx), e2 = fexp(a2 - mx);
      float d = __fdividef(1.f, e0 + e1 + e2);
      sm.scal[11] = e0 * d; sm.scal[12] = e1 * d; sm.scal[13] = e2 * d;
    }
    __syncthreads();                                               // 4

    // ---- write head addressing (reg row + LDS row dots)
    float ww0, ww1;
    {
      float beta = sm.scal[0], g = sm.scal[1], gamma = sm.scal[2];
      float s0 = sm.scal[3], s1 = sm.scal[4], s2 = sm.scal[5], kn = sm.scal[6];
      float d0 = 0.f, d1 = 0.f;
      #pragma unroll
      for (int bq = 0; bq < 16; ++bq) {
        float4 kv = *(const float4*)&sm.k[bq * 4];
        d0 = fmaf(M0[bq * 4],     kv.x, d0);
        d0 = fmaf(M0[bq * 4 + 1], kv.y, d0);
        d0 = fmaf(M0[bq * 4 + 2], kv.z, d0);
        d0 = fmaf(M0[bq * 4 + 3], kv.w, d0);
        float4 mv = *(const float4*)&sm.M1s[m1idx(bq, tid)];
        d1 = fmaf(mv.x, kv.x, d1); d1 = fmaf(mv.y, kv.y, d1);
        d1 = fmaf(mv.z, kv.z, d1); d1 = fmaf(mv.w, kv.w, d1);
      }
      float sim0 = beta * d0 / (sqrtf(n2_0) * kn + kEPS);
      float sim1 = beta * d1 / (sqrtf(n2_1) * kn + kEPS);
      address2(sm, tid, lane, wid, sim0, sim1, g, s0, s1, s2, gamma, wp0, wp1, ww0, ww1);
    }                                                              // 5,6,7

    // ---- memory update, fused with read-head dot + new row norms
    float dr0 = 0.f, dr1 = 0.f, nn0 = 0.f, nn1 = 0.f;
    #pragma unroll
    for (int bq = 0; bq < 16; ++bq) {
      float4 ev = *(const float4*)&sm.e[bq * 4];
      float4 av = *(const float4*)&sm.a[bq * 4];
      float4 kv = *(const float4*)&sm.kr[bq * 4];
      // reg row
      {
        float m = fmaf(ww0, fmaf(-ev.x, M0[bq * 4], av.x), M0[bq * 4]);
        M0[bq * 4] = m; dr0 = fmaf(m, kv.x, dr0); nn0 = fmaf(m, m, nn0);
      }
      {
        float m = fmaf(ww0, fmaf(-ev.y, M0[bq * 4 + 1], av.y), M0[bq * 4 + 1]);
        M0[bq * 4 + 1] = m; dr0 = fmaf(m, kv.y, dr0); nn0 = fmaf(m, m, nn0);
      }
      {
        float m = fmaf(ww0, fmaf(-ev.z, M0[bq * 4 + 2], av.z), M0[bq * 4 + 2]);
        M0[bq * 4 + 2] = m; dr0 = fmaf(m, kv.z, dr0); nn0 = fmaf(m, m, nn0);
      }
      {
        float m = fmaf(ww0, fmaf(-ev.w, M0[bq * 4 + 3], av.w), M0[bq * 4 + 3]);
        M0[bq * 4 + 3] = m; dr0 = fmaf(m, kv.w, dr0); nn0 = fmaf(m, m, nn0);
      }
      // LDS row (read-modify-write, same thread, lane-contiguous b128)
      int fi = m1idx(bq, tid);
      float4 mv = *(const float4*)&sm.M1s[fi];
      float4 nm;
      nm.x = fmaf(ww1, fmaf(-ev.x, mv.x, av.x), mv.x);
      dr1 = fmaf(nm.x, kv.x, dr1); nn1 = fmaf(nm.x, nm.x, nn1);
      nm.y = fmaf(ww1, fmaf(-ev.y, mv.y, av.y), mv.y);
      dr1 = fmaf(nm.y, kv.y, dr1); nn1 = fmaf(nm.y, nm.y, nn1);
      nm.z = fmaf(ww1, fmaf(-ev.z, mv.z, av.z), mv.z);
      dr1 = fmaf(nm.z, kv.z, dr1); nn1 = fmaf(nm.z, nm.z, nn1);
      nm.w = fmaf(ww1, fmaf(-ev.w, mv.w, av.w), mv.w);
      dr1 = fmaf(nm.w, kv.w, dr1); nn1 = fmaf(nm.w, nm.w, nn1);
      *(float4*)&sm.M1s[fi] = nm;
    }

    // ---- read head addressing (prev weights = write weights)
    float wr0, wr1;
    {
      float beta = sm.scal[8], g = sm.scal[9], gamma = sm.scal[10];
      float s0 = sm.scal[11], s1 = sm.scal[12], s2 = sm.scal[13], kn = sm.scal[14];
      float sim0 = beta * dr0 / (sqrtf(nn0) * kn + kEPS);
      float sim1 = beta * dr1 / (sqrtf(nn1) * kn + kEPS);
      address2(sm, tid, lane, wid, sim0, sim1, g, s0, s1, s2, gamma, ww0, ww1, wr0, wr1);
    }                                                              // 8,9,10
    wp0 = wr0; wp1 = wr1; n2_0 = nn0; n2_1 = nn1;   // carry state

    // ---- read vector r[j] = sum_n w_r[n] M[n][j]
    // two 32-column butterfly passes; register peak cur[16]. All indices
    // compile-time (rule #20).
    {
      // pass A: columns 0..31
      {
        float cur[16];
        const int b0 = lane & 1;
        #pragma unroll
        for (int qq = 0; qq < 8; ++qq) {
          float4 mv = *(const float4*)&sm.M1s[m1idx(qq, tid)];
          float v0 = fmaf(wr0, M0[4 * qq],     wr1 * mv.x);
          float v1 = fmaf(wr0, M0[4 * qq + 1], wr1 * mv.y);
          float keep = b0 ? v1 : v0, send = b0 ? v0 : v1;
          cur[2 * qq] = keep + __shfl_xor(send, 1);
          float v2 = fmaf(wr0, M0[4 * qq + 2], wr1 * mv.z);
          float v3 = fmaf(wr0, M0[4 * qq + 3], wr1 * mv.w);
          keep = b0 ? v3 : v2; send = b0 ? v2 : v3;
          cur[2 * qq + 1] = keep + __shfl_xor(send, 1);
        }
        #pragma unroll
        for (int st = 1; st < 5; ++st) {
          const int d = 1 << st;
          const int bb = (lane >> st) & 1;
          #pragma unroll
          for (int q = 0; q < (16 >> st); ++q) {
            float x0 = cur[2 * q], x1 = cur[2 * q + 1];
            float keep = bb ? x1 : x0, send = bb ? x0 : x1;
            cur[q] = keep + __shfl_xor(send, d);
          }
        }
        float tot = cur[0] + __shfl_xor(cur[0], 32);
        if (lane < 32) sm.part[wid][lane] = tot;
      }
      // pass B: columns 32..63
      {
        float cur[16];
        const int b0 = lane & 1;
        #pragma unroll
        for (int qq = 0; qq < 8; ++qq) {
          float4 mv = *(const float4*)&sm.M1s[m1idx(8 + qq, tid)];
          float v0 = fmaf(wr0, M0[32 + 4 * qq],     wr1 * mv.x);
          float v1 = fmaf(wr0, M0[32 + 4 * qq + 1], wr1 * mv.y);
          float keep = b0 ? v1 : v0, send = b0 ? v0 : v1;
          cur[2 * qq] = keep + __shfl_xor(send, 1);
          float v2 = fmaf(wr0, M0[32 + 4 * qq + 2], wr1 * mv.z);
          float v3 = fmaf(wr0, M0[32 + 4 * qq + 3], wr1 * mv.w);
          keep = b0 ? v3 : v2; send = b0 ? v2 : v3;
          cur[2 * qq + 1] = keep + __shfl_xor(send, 1);
        }
        #pragma unroll
        for (int st = 1; st < 5; ++st) {
          const int d = 1 << st;
          const int bb = (lane >> st) & 1;
          #pragma unroll
          for (int q = 0; q < (16 >> st); ++q) {
            float x0 = cur[2 * q], x1 = cur[2 * q + 1];
            float keep = bb ? x1 : x0, send = bb ? x0 : x1;
            cur[q] = keep + __shfl_xor(send, d);
          }
        }
        float tot = cur[0] + __shfl_xor(cur[0], 32);
        if (lane < 32) sm.part[wid][32 + lane] = tot;
      }
    }
    __syncthreads();                                               // 11
    if (tid < kMV) {
      float s = sm.part[0][tid];
      #pragma unroll
      for (int w = 1; w < NW; ++w) s += sm.part[w][tid];
      sm.r[tid] = s;
    }
    __syncthreads();                                               // 12

    // ---- output: sigmoid([c, r] @ Wf + bf); 64 outs x 8 partials of 40
    {
      const int j = tid & 63, p = tid >> 6;
      float s = 0.f;
      if constexpr (PACKED) {
        const TD* row = pWfT + j * (kC + kMV) + p * 40;
        #pragma unroll
        for (int q = 0; q < 5; ++q) {
          int idx0 = p * 40 + 8 * q;   // multiple of 8; c/r boundary chunk-aligned
          const float* src = (idx0 < kC) ? &sm.c[idx0] : &sm.r[idx0 - kC];
          float f[8]; ld8(row + 8 * q, f);
          float4 va = *(const float4*)src;
          float4 vb = *(const float4*)(src + 4);
          s = fmaf(va.x, f[0], s); s = fmaf(va.y, f[1], s);
          s = fmaf(va.z, f[2], s); s = fmaf(va.w, f[3], s);
          s = fmaf(vb.x, f[4], s); s = fmaf(vb.y, f[5], s);
          s = fmaf(vb.z, f[6], s); s = fmaf(vb.w, f[7], s);
        }
      } else {
        #pragma unroll
        for (int i = 0; i < 40; ++i) {
          int idx = p * 40 + i;
          float v = (idx < kC) ? sm.c[idx] : sm.r[idx - kC];
          s = fmaf(v, ldf(Wf, idx * kOUT + j), s);
        }
      }
      sm.part[p][j] = s;
    }
    __syncthreads();                                               // 13
    if (tid < kOUT) {
      float s = sm.bfS[tid];
      #pragma unroll
      for (int p = 0; p < 8; ++p) s += sm.part[p][tid];
      stf(out, (b * kT + t) * kOUT + tid, sigmoidf_(s));
    }
    __syncthreads();                                               // 14
  }
}

template <typename TD, int WANT, int PACKED>
static void launch_variant(void* const* d_in, void* d_out, const int* flag,
                           const void* pk, hipStream_t stream) {
  ntm_fused<TD, WANT, PACKED><<<dim3(kB), dim3(NT), 0, stream>>>(
      (const TD*)d_in[0], (const TD*)d_in[1], (const TD*)d_in[2],
      (const TD*)d_in[3], (const TD*)d_in[4], (const TD*)d_in[5],
      (const TD*)d_in[6], (const TD*)d_in[7], (const TD*)d_in[8],
      (const TD*)d_in[9], (const TD*)d_in[10], (const TD*)d_in[11],
      (const TD*)pk, (TD*)d_out, flag);
}

extern "C" void kernel_launch(void* const* d_in, const int* in_sizes, int n_in,
                              void* d_out, int out_size, void* d_ws, size_t ws_size,
                              hipStream_t stream) {
  (void)in_sizes; (void)n_in; (void)out_size;
  int* flag = (int*)d_ws;
  detect_dtype<<<dim3(1), dim3(64), 0, stream>>>(d_in[10], flag);
  if (ws_size >= kWsNeeded) {
    void* pk = (void*)((char*)d_ws + 256);
    repack_w<__hip_bfloat16, 1><<<dim3(256), dim3(256), 0, stream>>>(
        (const __hip_bfloat16*)d_in[1], (const __hip_bfloat16*)d_in[5],
        (const __hip_bfloat16*)d_in[3], (const __hip_bfloat16*)d_in[7],
        (__hip_bfloat16*)pk, flag);
    repack_w<float, 0><<<dim3(256), dim3(256), 0, stream>>>(
        (const float*)d_in[1], (const float*)d_in[5],
        (const float*)d_in[3], (const float*)d_in[7],
        (float*)pk, flag);
    launch_variant<__hip_bfloat16, 1, 1>(d_in, d_out, flag, pk, stream);
    launch_variant<float, 0, 1>(d_in, d_out, flag, pk, stream);
  } else {
    launch_variant<__hip_bfloat16, 1, 0>(d_in, d_out, flag, nullptr, stream);
    launch_variant<float, 0, 0>(d_in, d_out, flag, nullptr, stream);
  }
}